// Round 5
// baseline (556.152 us; speedup 1.0000x reference)
//
#include <hip/hip_runtime.h>
#include <math.h>

// GreedyRouter: softmax gating + top-8 + renormalize + histogram.
// Insight: renormalized top-k softmax == softmax over only the top-k logits
// (full-row denominator cancels), so we never compute the full softmax.
//
// R4: 2 lanes per token -> 2x wave parallelism. R3's counters: occupancy
// 34% (grid 1024 blocks = 16 waves/CU, ALL resident; one-token-per-thread
// caps TLP), VALU 35%, HBM 37% -> pipes serialized per wave. Fix: lane
// pair (r,h) splits each token's 256 cols; each lane keeps a sorted top-8
// of its 128-col subset; one shfl_xor(32) + static bitonic merge-16 at
// the end recovers the exact global top-8 (strict (v desc, idx asc) total
// order == jax tie-break). Grid doubles to 2048 blocks = 32 waves/CU.
// Keeps R3's rotated register double-buffer (counted vmcnt, stores never
// awaited) and barrier-free per-wave LDS staging.

constexpr int NEXP   = 256;   // experts
constexpr int TOPK   = 8;
constexpr int TPB    = 256;   // 4 waves per block
constexpr int WAVES  = TPB / 64;
constexpr int TPW    = 32;    // tokens per wave (64 lanes / 2 per token)
constexpr int TPBLK  = WAVES * TPW;    // 128 tokens per block
constexpr int CHUNK  = 16;    // columns staged per pipeline stage
constexpr int NCHUNK = NEXP / CHUNK;   // 16
constexpr int HALF   = CHUNK / 2;      // 8 cols consumed per lane per chunk
constexpr int STRIDE = CHUNK + 1;      // 17: read banks 2-way across halves, free
constexpr int F4T    = 2;     // float4 loads per lane per chunk (32 rows x 64B)

__global__ __launch_bounds__(TPB, 8) void router_kernel(
    const float* __restrict__ logits,
    float* __restrict__ out_logits,
    float* __restrict__ out_w,
    float* __restrict__ out_id,
    float* __restrict__ counts)
{
    __shared__ float tile[WAVES][TPW * STRIDE];  // 4 x 2176 B = 8704 B
    __shared__ int   hist[NEXP];                 // 1024 B -> 9728 B total

    const int tid  = threadIdx.x;
    const int wave = tid >> 6;
    const int lane = tid & 63;
    const int r    = lane & 31;   // token within wave
    const int h    = lane >> 5;   // column half (0: cols j, 1: cols 8+j)
    const int tokw0 = blockIdx.x * TPBLK + wave * TPW;

    hist[tid] = 0;
    __syncthreads();   // hist zeroed before any wave's atomics

    // per-lane sorted top-8 over this lane's 128-col subset; strict '>' +
    // ascending index scan => sorted by (v desc, idx asc) within subset.
    float v[TOPK];
    int   id[TOPK];
#pragma unroll
    for (int k = 0; k < TOPK; ++k) { v[k] = -INFINITY; id[k] = 0; }

    // Staging addresses: f = lane + 64*i -> row rr = f/4 (0..31), col-group
    // cc = f%4. Wave-load = 16 rows x 64B segments per instr (coalesced).
    size_t gbase[F4T];
    int    lbase[F4T];
#pragma unroll
    for (int i = 0; i < F4T; ++i) {
        int f  = lane + 64 * i;
        int rr = f >> 2;
        int cc = f & 3;
        gbase[i] = (size_t)(tokw0 + rr) * NEXP + cc * 4;
        lbase[i] = rr * STRIDE + cc * 4;
    }

    // Named rotated buffers (runtime-indexed arrays would go to scratch).
    float4 xA[F4T], xB[F4T];

    // One step: chunk C sits in XC (loads issued one step earlier => oldest
    // outstanding vmcnt entries; compiler emits counted wait, stores and
    // L(C+1) stay in flight). Then commit to LDS + passthrough, consume.
#define STEP(C, XC, XN)                                                     \
    {                                                                       \
        const int c_ = (C);                                                 \
        if (c_ + 1 < NCHUNK) {                                              \
            const int off = (c_ + 1) * CHUNK;                               \
            _Pragma("unroll")                                               \
            for (int i = 0; i < F4T; ++i)                                   \
                XN[i] = *(const float4*)(logits + gbase[i] + off);          \
        }                                                                   \
        {                                                                   \
            const int off = c_ * CHUNK;                                     \
            _Pragma("unroll")                                               \
            for (int i = 0; i < F4T; ++i) {                                 \
                *(float4*)(out_logits + gbase[i] + off) = XC[i];            \
                float* t = &tile[wave][lbase[i]];                           \
                t[0] = XC[i].x; t[1] = XC[i].y;                             \
                t[2] = XC[i].z; t[3] = XC[i].w;                             \
            }                                                               \
        }                                                                   \
        const float* row = &tile[wave][r * STRIDE + h * HALF];              \
        const int c0 = c_ * CHUNK + h * HALF;                               \
        _Pragma("unroll")                                                   \
        for (int j = 0; j < HALF; ++j) {                                    \
            float xx = row[j];                                              \
            int   xi = c0 + j;                                              \
            _Pragma("unroll")                                               \
            for (int k = 0; k < TOPK; ++k) {                                \
                bool  gt = xx > v[k];                                       \
                float tv = v[k];                                            \
                int   ti = id[k];                                           \
                v[k]  = gt ? xx : tv;                                       \
                id[k] = gt ? xi : ti;                                       \
                xx    = gt ? tv : xx;                                       \
                xi    = gt ? ti : xi;                                       \
            }                                                               \
        }                                                                   \
    }

    // ---- prologue: issue chunk 0 loads into xA ----
#pragma unroll
    for (int i = 0; i < F4T; ++i)
        xA[i] = *(const float4*)(logits + gbase[i]);

    // ---- main pipeline: zero barriers, stores never awaited ----
#pragma unroll 1
    for (int c = 0; c < NCHUNK; c += 2) {
        STEP(c,     xA, xB);
        STEP(c + 1, xB, xA);
    }
#undef STEP

    // ---- merge the lane pair's two sorted-8 lists (exact top-8) ----
    float pv[TOPK]; int pid[TOPK];
#pragma unroll
    for (int k = 0; k < TOPK; ++k) {
        pv[k]  = __shfl_xor(v[k],  32, 64);
        pid[k] = __shfl_xor(id[k], 32, 64);
    }
    // Bitonic: A desc ++ reverse(B desc) is bitonic; stage d=8 pushes the
    // top-8 SET into m[0..7] (bitonic), then full merge sorts it. (v,idx)
    // pairs are unique => strict total order => exact, deterministic, and
    // identical on both lanes of the pair.
    float mv[16]; int mi[16];
#pragma unroll
    for (int k = 0; k < TOPK; ++k) { mv[k] = v[k];      mi[k] = id[k]; }
#pragma unroll
    for (int k = 0; k < TOPK; ++k) { mv[8 + k] = pv[7 - k]; mi[8 + k] = pid[7 - k]; }

#define CE(I, J)                                                            \
    {                                                                       \
        bool sw = (mv[J] > mv[I]) || ((mv[J] == mv[I]) && (mi[J] < mi[I])); \
        float tv = mv[I]; int ti = mi[I];                                   \
        mv[I] = sw ? mv[J] : mv[I];  mi[I] = sw ? mi[J] : mi[I];            \
        mv[J] = sw ? tv : mv[J];     mi[J] = sw ? ti : mi[J];               \
    }
    CE(0, 8)  CE(1, 9)  CE(2, 10) CE(3, 11) CE(4, 12) CE(5, 13) CE(6, 14) CE(7, 15)
    CE(0, 4)  CE(1, 5)  CE(2, 6)  CE(3, 7)
    CE(0, 2)  CE(1, 3)  CE(4, 6)  CE(5, 7)
    CE(0, 1)  CE(2, 3)  CE(4, 5)  CE(6, 7)
#undef CE

    // ---- softmax over the selected 8 (== renormalized full softmax) ----
    float e[TOPK];
    float s = 0.f;
#pragma unroll
    for (int k = 0; k < TOPK; ++k) { e[k] = __expf(mv[k] - mv[0]); s += e[k]; }
    const float inv = 1.0f / s;

    // Each lane of the pair writes half the outputs (fully coalesced 1KB
    // wave-stores). Indices in both ternary arms are compile-time.
    const size_t token = (size_t)(tokw0 + r);
    float4 wq, iq;
    wq.x = (h ? e[4] : e[0]) * inv;  iq.x = (float)(h ? mi[4] : mi[0]);
    wq.y = (h ? e[5] : e[1]) * inv;  iq.y = (float)(h ? mi[5] : mi[1]);
    wq.z = (h ? e[6] : e[2]) * inv;  iq.z = (float)(h ? mi[6] : mi[2]);
    wq.w = (h ? e[7] : e[3]) * inv;  iq.w = (float)(h ? mi[7] : mi[3]);
    *(float4*)(out_w  + token * TOPK + h * 4) = wq;
    *(float4*)(out_id + token * TOPK + h * 4) = iq;

    // histogram: each lane contributes its half's 4 ids (total 8 per token)
#pragma unroll
    for (int k = 0; k < 4; ++k)
        atomicAdd(&hist[h ? mi[4 + k] : mi[k]], 1);
    __syncthreads();
    // one global atomic per (block, expert)
    atomicAdd(&counts[tid], (float)hist[tid]);
}

extern "C" void kernel_launch(void* const* d_in, const int* in_sizes, int n_in,
                              void* d_out, int out_size, void* d_ws, size_t ws_size,
                              hipStream_t stream) {
    const float* logits = (const float*)d_in[0];
    const int n_tokens  = in_sizes[0] / NEXP;

    float* out        = (float*)d_out;
    float* out_logits = out;
    float* out_w      = out_logits + (size_t)n_tokens * NEXP;
    float* out_id     = out_w      + (size_t)n_tokens * TOPK;
    float* counts     = out_id     + (size_t)n_tokens * TOPK;

    // d_out is re-poisoned to 0xAA before every launch; histogram needs zeros.
    hipMemsetAsync(counts, 0, NEXP * sizeof(float), stream);

    const int blocks = n_tokens / TPBLK;  // 262144/128 = 2048
    router_kernel<<<blocks, TPB, 0, stream>>>(logits, out_logits, out_w,
                                              out_id, counts);
}